// Round 1
// baseline (199.874 us; speedup 1.0000x reference)
//
#include <hip/hip_runtime.h>

#define BB 32
#define LL 512
#define TT 48
#define START_ID 46
#define END_ID 47

constexpr int BLT = BB * LL * TT;            // 786432 feature elements
constexpr unsigned NSC  = 37748736u;         // B*L*T*T scores elements
constexpr unsigned NGRP = 9437183u;          // float4 groups at scores idx 3+4k

typedef __fp16   f16x8 __attribute__((ext_vector_type(8)));
typedef float    f32x4 __attribute__((ext_vector_type(4)));
typedef unsigned u32x4 __attribute__((ext_vector_type(4)));

__device__ __forceinline__ float fexp2(float x) { return __builtin_amdgcn_exp2f(x); }
__device__ __forceinline__ float flog2(float x) { return __builtin_amdgcn_logf(x); }
__device__ __forceinline__ unsigned pk2(float a, float b) {
  return __builtin_bit_cast(unsigned, __builtin_amdgcn_cvt_pkrtz(a, b));
}
// f16x8 operand with upper K-half zeroed (K=16 content inside a K=32 MFMA)
__device__ __forceinline__ f16x8 mk8(float a, float b, float c, float d) {
  u32x4 u; u.x = pk2(a, b); u.y = pk2(c, d); u.z = 0u; u.w = 0u;
  return __builtin_bit_cast(f16x8, u);
}
__device__ __forceinline__ f32x4 MF(f16x8 a, f16x8 b, f32x4 c) {
  return __builtin_amdgcn_mfma_f32_16x16x32_f16(a, b, c, 0, 0, 0);
}

// ---------------- batched linear-domain CRF recursion: one wave = 16 batches ----
// U (48 x 16 per wave) evolves as U <- exp(f_t) ⊙ (E·U), E = exp(trans), f16
// inputs / fp32 accum, per-column power-of-2 rescale with lagged column max.
__device__ __attribute__((noinline)) void crf_rec_wave(
    const float* __restrict__ feat, const float* __restrict__ trans,
    const int* __restrict__ seqLens, float* lzout, int ct, int lane)
{
  constexpr float LOG2E = 1.4426950408889634f;
  constexpr float LN2   = 0.6931471805599453f;
  __builtin_amdgcn_s_setprio(1);

  const int col = lane & 15, grp = lane >> 4;
  const int rb  = grp * 4;                  // row base within a 16-tile (C/B/EF rows)
  const int myb = ct * 16 + col;            // my batch (column)
  const float* fb = feat + (size_t)myb * (LL * TT);

  // ---- A operands: E = exp(trans), 9 tiles, K zero-padded 16->32 ----
  // A[row=l&15][k=(l>>4)*8+e], e=0..3 data, e=4..7 zero (B uses same map => pairs ok)
  f16x8 A00,A01,A02,A10,A11,A12,A20,A21,A22;
#define LDA(V, RT, KT) { const float4 t4 = *(const float4*)(trans + ((RT)*16+col)*48 + (KT)*16 + rb); \
  V = mk8(fexp2(t4.x*LOG2E), fexp2(t4.y*LOG2E), fexp2(t4.z*LOG2E), fexp2(t4.w*LOG2E)); }
  LDA(A00,0,0) LDA(A01,0,1) LDA(A02,0,2)
  LDA(A10,1,0) LDA(A11,1,1) LDA(A12,1,2)
  LDA(A20,2,0) LDA(A21,2,1) LDA(A22,2,2)
#undef LDA
  // exp(trans[END,i]) for the final dot (f32, C-row indexing)
  f32x4 TE0, TE1, TE2;
#define LDT(V, RT) { const float4 t4 = *(const float4*)(trans + END_ID*48 + (RT)*16 + rb); \
  V.x = fexp2(t4.x*LOG2E); V.y = fexp2(t4.y*LOG2E); V.z = fexp2(t4.z*LOG2E); V.w = fexp2(t4.w*LOG2E); }
  LDT(TE0,0) LDT(TE1,1) LDT(TE2,2)
#undef LDT

  const int myLb1 = seqLens[myb] - 1;       // capture step, in [0, 511]
  int tmv = myLb1;
#pragma unroll
  for (int off = 1; off <= 32; off <<= 1) { const int o = __shfl_xor(tmv, off, 64); tmv = tmv > o ? tmv : o; }
  const int tmax = __builtin_amdgcn_readfirstlane(tmv);

  // ---- init: alpha0 = trans[:,START] + feat[:,0,:]  (log2 units) ----
  const float4 q0 = *(const float4*)(fb + rb);
  const float4 q1 = *(const float4*)(fb + 16 + rb);
  const float4 q2 = *(const float4*)(fb + 32 + rb);
  f32x4 AL0, AL1, AL2;
#define INITA(V, RT, Q) { \
  V.x = (trans[((RT)*16+rb+0)*48+START_ID] + Q.x)*LOG2E; \
  V.y = (trans[((RT)*16+rb+1)*48+START_ID] + Q.y)*LOG2E; \
  V.z = (trans[((RT)*16+rb+2)*48+START_ID] + Q.z)*LOG2E; \
  V.w = (trans[((RT)*16+rb+3)*48+START_ID] + Q.w)*LOG2E; }
  INITA(AL0,0,q0) INITA(AL1,1,q1) INITA(AL2,2,q2)
#undef INITA
  float m = fmaxf(fmaxf(fmaxf(AL0.x,AL0.y),fmaxf(AL0.z,AL0.w)),
            fmaxf(fmaxf(fmaxf(AL1.x,AL1.y),fmaxf(AL1.z,AL1.w)),
                  fmaxf(fmaxf(AL2.x,AL2.y),fmaxf(AL2.z,AL2.w))));
  m = fmaxf(m, __shfl_xor(m, 16, 64));
  m = fmaxf(m, __shfl_xor(m, 32, 64));
  float sigma = m;                           // log2-scale; true u = V * 2^sigma

  f32x4 P0, P1, P2;                          // current state (fp32, normalized)
  P0.x = fexp2(AL0.x - m); P0.y = fexp2(AL0.y - m); P0.z = fexp2(AL0.z - m); P0.w = fexp2(AL0.w - m);
  P1.x = fexp2(AL1.x - m); P1.y = fexp2(AL1.y - m); P1.z = fexp2(AL1.z - m); P1.w = fexp2(AL1.w - m);
  P2.x = fexp2(AL2.x - m); P2.y = fexp2(AL2.y - m); P2.z = fexp2(AL2.z - m); P2.w = fexp2(AL2.w - m);

#define CAPT(T) \
  { const bool cap = ((T) == myLb1); \
    if (__any((int)cap)) { \
      float part =       P0.x*TE0.x; \
      part = fmaf(P0.y,TE0.y,part); part = fmaf(P0.z,TE0.z,part); part = fmaf(P0.w,TE0.w,part); \
      part = fmaf(P1.x,TE1.x,part); part = fmaf(P1.y,TE1.y,part); part = fmaf(P1.z,TE1.z,part); part = fmaf(P1.w,TE1.w,part); \
      part = fmaf(P2.x,TE2.x,part); part = fmaf(P2.y,TE2.y,part); part = fmaf(P2.z,TE2.z,part); part = fmaf(P2.w,TE2.w,part); \
      part += __shfl_xor(part, 16, 64); part += __shfl_xor(part, 32, 64); \
      if (cap && grp == 0) lzout[myb] = (flog2(part) + sigma) * LN2; } }

  CAPT(0)                                    // batches with Lb == 1

  // pack U0 (C-fragment -> next B-fragment is in-lane for 16x16 shapes)
  f16x8 B0 = mk8(P0.x,P0.y,P0.z,P0.w);
  f16x8 B1 = mk8(P1.x,P1.y,P1.z,P1.w);
  f16x8 B2 = mk8(P2.x,P2.y,P2.z,P2.w);

  // EFS(1) = exp2(f_1*LOG2E - k_1), k_1 = 0 (U0 max = 1, growth/step <= 2^13.8)
  const float4 y0 = *(const float4*)(fb + 48 + rb);
  const float4 y1 = *(const float4*)(fb + 48 + 16 + rb);
  const float4 y2 = *(const float4*)(fb + 48 + 32 + rb);
  f32x4 E0, E1, E2;
  E0.x = fexp2(y0.x*LOG2E); E0.y = fexp2(y0.y*LOG2E); E0.z = fexp2(y0.z*LOG2E); E0.w = fexp2(y0.w*LOG2E);
  E1.x = fexp2(y1.x*LOG2E); E1.y = fexp2(y1.y*LOG2E); E1.z = fexp2(y1.z*LOG2E); E1.w = fexp2(y1.w*LOG2E);
  E2.x = fexp2(y2.x*LOG2E); E2.y = fexp2(y2.y*LOG2E); E2.z = fexp2(y2.z*LOG2E); E2.w = fexp2(y2.w*LOG2E);

  // feat prefetch ring (depth 2): Xb = f(2); Xa filled in-loop
  float4 Xb0 = *(const float4*)(fb + 96 + rb);
  float4 Xb1 = *(const float4*)(fb + 96 + 16 + rb);
  float4 Xb2 = *(const float4*)(fb + 96 + 32 + rb);
  float4 Xa0, Xa1, Xa2;

#define STEP(XC0,XC1,XC2, XN0,XN1,XN2) \
  { const int tp = (t + 2 <= 511) ? (t + 2) : 511; \
    XN0 = *(const float4*)(fb + tp*48 + rb); \
    XN1 = *(const float4*)(fb + tp*48 + 16 + rb); \
    XN2 = *(const float4*)(fb + tp*48 + 32 + rb); \
    const f32x4 zz = {0.f, 0.f, 0.f, 0.f}; \
    P0 = MF(A00,B0,zz); P1 = MF(A10,B0,zz); P2 = MF(A20,B0,zz); \
    P0 = MF(A01,B1,P0); P1 = MF(A11,B1,P1); P2 = MF(A21,B1,P2); \
    P0 = MF(A02,B2,P0); P1 = MF(A12,B2,P1); P2 = MF(A22,B2,P2); \
    P0.x *= E0.x; P0.y *= E0.y; P0.z *= E0.z; P0.w *= E0.w; \
    P1.x *= E1.x; P1.y *= E1.y; P1.z *= E1.z; P1.w *= E1.w; \
    P2.x *= E2.x; P2.y *= E2.y; P2.z *= E2.z; P2.w *= E2.w; \
    CAPT(t) \
    float cm = fmaxf(fmaxf(fmaxf(P0.x,P0.y),fmaxf(P0.z,P0.w)), \
               fmaxf(fmaxf(fmaxf(P1.x,P1.y),fmaxf(P1.z,P1.w)), \
                     fmaxf(fmaxf(P2.x,P2.y),fmaxf(P2.z,P2.w)))); \
    cm = fmaxf(cm, __shfl_xor(cm, 16, 64)); \
    cm = fmaxf(cm, __shfl_xor(cm, 32, 64)); \
    const float kf = (float)((int)((__float_as_uint(cm) >> 23) & 255u) - 127); \
    sigma += kf; \
    B0 = mk8(P0.x,P0.y,P0.z,P0.w); \
    B1 = mk8(P1.x,P1.y,P1.z,P1.w); \
    B2 = mk8(P2.x,P2.y,P2.z,P2.w); \
    const float nk = -kf; \
    E0.x = fexp2(fmaf(XC0.x,LOG2E,nk)); E0.y = fexp2(fmaf(XC0.y,LOG2E,nk)); \
    E0.z = fexp2(fmaf(XC0.z,LOG2E,nk)); E0.w = fexp2(fmaf(XC0.w,LOG2E,nk)); \
    E1.x = fexp2(fmaf(XC1.x,LOG2E,nk)); E1.y = fexp2(fmaf(XC1.y,LOG2E,nk)); \
    E1.z = fexp2(fmaf(XC1.z,LOG2E,nk)); E1.w = fexp2(fmaf(XC1.w,LOG2E,nk)); \
    E2.x = fexp2(fmaf(XC2.x,LOG2E,nk)); E2.y = fexp2(fmaf(XC2.y,LOG2E,nk)); \
    E2.z = fexp2(fmaf(XC2.z,LOG2E,nk)); E2.w = fexp2(fmaf(XC2.w,LOG2E,nk)); }

  if (tmax >= 1) {
    int t = 1;
    for (;;) {
      STEP(Xb0,Xb1,Xb2, Xa0,Xa1,Xa2)
      if (++t > tmax) break;
      STEP(Xa0,Xa1,Xa2, Xb0,Xb1,Xb2)
      if (++t > tmax) break;
    }
  }
#undef STEP
#undef CAPT
  __builtin_amdgcn_s_setprio(0);
}

// ---------------- fused kernel: block 0 = recursion (2 waves) + reduce, rest writers ----
__global__ __launch_bounds__(256) void crf_fused3_kernel(
    const float* __restrict__ feat, const float* __restrict__ trans,
    const int* __restrict__ seqLens, float* __restrict__ out)
{
  __shared__ __align__(16) float lds[2304];  // writer: trans stage; block 0: logZ[32]
  const int blk = blockIdx.x;
  const int tid = threadIdx.x;

  if (blk == 0) {
    if (tid < 128) crf_rec_wave(feat, trans, seqLens, lds, tid >> 6, tid & 63);
    __syncthreads();
    if (tid < 64) {
      float v = (tid < 32) ? lds[tid] : 0.0f;
#pragma unroll
      for (int off = 32; off; off >>= 1) v += __shfl_xor(v, off, 64);
      if (tid == 0) out[0] = v;                                   // logZ
      else if (tid <= 3) out[tid] = feat[0] + trans[tid - 1];     // scores_flat[0..2]
      else if (tid == 4) out[NSC] = feat[BLT - 1] + trans[2303];  // scores_flat last
    }
    return;
  }

  // scores writer: out[1+s] = feat[s/48] + trans[s%2304], s = 3+4k .. 6+4k
  for (int s = tid; s < 2304; s += 256) lds[s] = trans[s];
  __syncthreads();
  const unsigned kstride = (gridDim.x - 1u) * 256u;
  unsigned k = (unsigned)(blk - 1) * 256u + (unsigned)tid;
  for (; k < NGRP; k += kstride) {
    const unsigned idx = 3u + 4u * k;           // scores flat index of element 0
    const unsigned r0 = idx / 48u;              // feature row
    const unsigned j0 = idx - r0 * 48u;
    const unsigned i0 = r0 % 48u;
    const unsigned rn = (r0 + 1u < (unsigned)BLT) ? r0 + 1u : (unsigned)(BLT - 1);
    const float fa = feat[r0];
    const float fn = feat[rn];
    const unsigned i1 = (i0 + 1u < 48u) ? i0 + 1u : 0u;
    float v[4];
#pragma unroll
    for (int e = 0; e < 4; ++e) {
      const unsigned j = j0 + (unsigned)e;
      const bool wr = j >= 48u;
      const unsigned jj = wr ? j - 48u : j;
      v[e] = (wr ? fn : fa) + lds[(wr ? i1 : i0) * 48u + jj];
    }
    float4 o; o.x = v[0]; o.y = v[1]; o.z = v[2]; o.w = v[3];
    *(float4*)(out + 4u + 4u * (size_t)k) = o;
  }
}

extern "C" void kernel_launch(void* const* d_in, const int* in_sizes, int n_in,
                              void* d_out, int out_size, void* d_ws, size_t ws_size,
                              hipStream_t stream) {
  const float* feat    = (const float*)d_in[0];
  const float* trans   = (const float*)d_in[1];
  const int*   seqLens = (const int*)d_in[2];
  float* out = (float*)d_out;
  hipLaunchKernelGGL(crf_fused3_kernel, dim3(2048), dim3(256), 0, stream,
                     feat, trans, seqLens, out);
}

// Round 2
// 88.981 us; speedup vs baseline: 2.2462x; 2.2462x over previous
//
#include <hip/hip_runtime.h>

#define BB 32
#define LL 512
#define TT 48
#define START_ID 46
#define END_ID 47

constexpr int   BLT  = BB * LL * TT;        // 786432 feature rows-elements
constexpr unsigned NSC = 37748736u;         // B*L*T*T scores elements
constexpr unsigned NGRP = 9437183u;         // float4 groups at scores idx 3+4k

typedef __fp16 f16x2 __attribute__((ext_vector_type(2)));

__device__ __forceinline__ float fexp2(float x) { return __builtin_amdgcn_exp2f(x); }
__device__ __forceinline__ float flog2(float x) { return __builtin_amdgcn_logf(x); }
__device__ __forceinline__ float rfirst(float x) {
  return __uint_as_float(__builtin_amdgcn_readfirstlane(__float_as_uint(x)));
}
__device__ __forceinline__ float fdot2(f16x2 a, f16x2 b, float c) {
  return __builtin_amdgcn_fdot2(a, b, c, false);
}
__device__ __forceinline__ f16x2 bc(unsigned u) { return __builtin_bit_cast(f16x2, u); }
// neighbor-swap lane^1 via DPP quad_perm (pure VALU, no LDS round-trip)
__device__ __forceinline__ float dpp_xor1(float x) {
  return __int_as_float(__builtin_amdgcn_update_dpp(
      __float_as_int(x), __float_as_int(x), 0xB1, 0xF, 0xF, true));
}

// async global->LDS DMA: 16B/lane, LDS dest = uniform base + lane*16
#define GLD16(gp, lp)                                                        \
  __builtin_amdgcn_global_load_lds(                                          \
      (const __attribute__((address_space(1))) unsigned int*)(gp),           \
      (__attribute__((address_space(3))) unsigned int*)(lp), 16, 0, 0)

// ---------------- recursion body: noinline => own register allocation ----------------
__device__ __attribute__((noinline)) void crf_recursion_body(
    const float* __restrict__ feat, const float* __restrict__ trans,
    const int* __restrict__ seqLens, float* __restrict__ ws,
    float* lds, int blk, int lane)
{
  constexpr float LOG2E = 1.4426950408889634f;
  // T5: this wave is a 512-step latency chain sharing its CU with ~28 writer
  // waves; win every contested issue slot. Writer waves still fill our
  // dependency-stall cycles (setprio only arbitrates when both are ready).
  __builtin_amdgcn_s_setprio(1);

  const int ii = lane < 47 ? lane : 47;       // lanes 48..63 mirror lane 47 (never read)
  const char* gbase = (const char*)(feat + (size_t)blk * (LL * TT));
  const int Lb = seqLens[blk];                // in [1, 512]

  // issue chunk 0 staging immediately (no VGPR cost)
#pragma unroll
  for (int w = 0; w < 6; ++w)
    GLD16(gbase + w * 1024 + lane * 16, (char*)&lds[0] + w * 1024);

  // packed exp(trans) as 24 named f16x2 scalars
  f16x2 E00,E01,E02,E03,E04,E05,E06,E07,E08,E09,E10,E11,
        E12,E13,E14,E15,E16,E17,E18,E19,E20,E21,E22,E23;
#define LDE(V, J) { const float e0_ = fexp2(trans[ii*48 + 2*(J)]     * LOG2E); \
                    const float e1_ = fexp2(trans[ii*48 + 2*(J) + 1] * LOG2E); \
                    V = __builtin_amdgcn_cvt_pkrtz(e0_, e1_); }
  LDE(E00,0)  LDE(E01,1)  LDE(E02,2)  LDE(E03,3)  LDE(E04,4)  LDE(E05,5)
  LDE(E06,6)  LDE(E07,7)  LDE(E08,8)  LDE(E09,9)  LDE(E10,10) LDE(E11,11)
  LDE(E12,12) LDE(E13,13) LDE(E14,14) LDE(E15,15) LDE(E16,16) LDE(E17,17)
  LDE(E18,18) LDE(E19,19) LDE(E20,20) LDE(E21,21) LDE(E22,22) LDE(E23,23)
#undef LDE
  const float tS = trans[ii * 48 + START_ID];
  const float tE = trans[END_ID * 48 + ii];

  asm volatile("s_waitcnt vmcnt(0)" ::: "memory");   // chunk 0 resident
  __builtin_amdgcn_sched_barrier(0);

  const float f00 = lds[ii];
  float a2 = (tS + f00) * LOG2E;              // alpha in base-2 units
  float M2 = rfirst(a2) + 5.0f;               // anchor: lane0 p = 2^-5, all p in f16 normal range

  const int nch = (Lb + 31) >> 5;
  for (int c = 0; c < nch; ++c) {
    const bool pre = (c + 1 < nch);
    if (pre) {                                 // DMA next chunk into other half
      const char* g = gbase + (size_t)(c + 1) * 6144;
      char* l = (char*)&lds[((c + 1) & 1) * 1536];
#pragma unroll
      for (int w = 0; w < 6; ++w) GLD16(g + w * 1024 + lane * 16, l + w * 1024);
    }
    const int tend = ((c + 1) * 32 < Lb) ? (c + 1) * 32 : Lb;
    const int t0 = (c == 0 ? 1 : c * 32);
    const int base = (c & 1) * 1536 + ii;
    if (t0 < tend) {
      float f_cur = lds[base + (t0 - c * 32) * 48];
      for (int t = t0; t < tend; ++t) {
        const int lnxt = ((t + 1 < tend) ? t + 1 : t) - c * 32;
        const float f_nxt = lds[base + lnxt * 48];             // prefetch next step's f
        const float p  = fexp2(a2 - M2);
        const float pn = dpp_xor1(p);                          // p of lane^1
        const unsigned pku =
            __builtin_bit_cast(unsigned, __builtin_amdgcn_cvt_pkrtz(p, pn));
        // phase 1: batched uniform broadcasts (SGPRs)
        unsigned s00,s01,s02,s03,s04,s05,s06,s07,s08,s09,s10,s11,
                 s12,s13,s14,s15,s16,s17,s18,s19,s20,s21,s22,s23;
#define RL(K) __builtin_amdgcn_readlane(pku, (K))
        s00=RL(0);  s01=RL(2);  s02=RL(4);  s03=RL(6);
        s04=RL(8);  s05=RL(10); s06=RL(12); s07=RL(14);
        s08=RL(16); s09=RL(18); s10=RL(20); s11=RL(22);
        s12=RL(24); s13=RL(26); s14=RL(28); s15=RL(30);
        s16=RL(32); s17=RL(34); s18=RL(36); s19=RL(38);
        s20=RL(40); s21=RL(42); s22=RL(44); s23=RL(46);
#undef RL
        // phase 2: 24 x v_dot2_f32_f16 in 4 independent chains
        float d0, d1, d2, d3;
        d0 = fdot2(E00, bc(s00), 0.0f);
        d1 = fdot2(E01, bc(s01), 0.0f);
        d2 = fdot2(E02, bc(s02), 0.0f);
        d3 = fdot2(E03, bc(s03), 0.0f);
        d0 = fdot2(E04, bc(s04), d0);
        d1 = fdot2(E05, bc(s05), d1);
        d2 = fdot2(E06, bc(s06), d2);
        d3 = fdot2(E07, bc(s07), d3);
        d0 = fdot2(E08, bc(s08), d0);
        d1 = fdot2(E09, bc(s09), d1);
        d2 = fdot2(E10, bc(s10), d2);
        d3 = fdot2(E11, bc(s11), d3);
        d0 = fdot2(E12, bc(s12), d0);
        d1 = fdot2(E13, bc(s13), d1);
        d2 = fdot2(E14, bc(s14), d2);
        d3 = fdot2(E15, bc(s15), d3);
        d0 = fdot2(E16, bc(s16), d0);
        d1 = fdot2(E17, bc(s17), d1);
        d2 = fdot2(E18, bc(s18), d2);
        d3 = fdot2(E19, bc(s19), d3);
        d0 = fdot2(E20, bc(s20), d0);
        d1 = fdot2(E21, bc(s21), d1);
        d2 = fdot2(E22, bc(s22), d2);
        d3 = fdot2(E23, bc(s23), d3);
        const float dot = (d0 + d1) + (d2 + d3);
        a2 = fmaf(f_cur, LOG2E, M2 + flog2(dot));
        M2 = rfirst(a2) + 5.0f;
        f_cur = f_nxt;
      }
    }
    asm volatile("s_waitcnt vmcnt(0)" ::: "memory");  // next chunk's DMA landed
    __builtin_amdgcn_sched_barrier(0);
  }

  // finalize: logZ_b = LSE_i(alpha[Lb-1,i] + trans[END,i])
  float last2 = (lane < 48) ? (a2 + tE * LOG2E) : -3.0e38f;
  float m2 = last2;
#pragma unroll
  for (int off = 32; off; off >>= 1) m2 = fmaxf(m2, __shfl_xor(m2, off, 64));
  float e = (lane < 48) ? fexp2(last2 - m2) : 0.0f;
#pragma unroll
  for (int off = 32; off; off >>= 1) e += __shfl_xor(e, off, 64);
  if (lane == 0) ws[blk] = (m2 + flog2(e)) * 0.6931471805599453f;
  __builtin_amdgcn_s_setprio(0);
}

// ---------------- fused kernel: blocks 0..31 recursion, 32.. writer ----------------
__global__ __launch_bounds__(256) void crf_fused2_kernel(
    const float* __restrict__ feat, const float* __restrict__ trans,
    const int* __restrict__ seqLens, float* __restrict__ out,
    float* __restrict__ ws)
{
  __shared__ __align__(16) float lds[3072];   // recursion dbuf (12KB) / writer trans stage (9KB)
  const int blk = blockIdx.x;

  if (blk < BB) {
    if (threadIdx.x >= 64) return;
    crf_recursion_body(feat, trans, seqLens, ws, lds, blk, threadIdx.x);
    return;
  }

  // scores writer: out[1+s] = feat[s/48] + trans[s%2304], s = 3+4k .. 6+4k
  for (int s = threadIdx.x; s < 2304; s += 256) lds[s] = trans[s];
  __syncthreads();
  const unsigned kstride = (gridDim.x - BB) * 256u;
  unsigned k = (blk - BB) * 256u + threadIdx.x;
  for (; k < NGRP; k += kstride) {
    const unsigned idx = 3u + 4u * k;           // scores flat index of element 0
    const unsigned r0 = idx / 48u;              // feature row
    const unsigned j0 = idx - r0 * 48u;
    const unsigned i0 = r0 % 48u;
    const unsigned rn = (r0 + 1u < (unsigned)BLT) ? r0 + 1u : (unsigned)(BLT - 1);
    const float fa = feat[r0];
    const float fn = feat[rn];
    const unsigned i1 = (i0 + 1u < 48u) ? i0 + 1u : 0u;
    float v[4];
#pragma unroll
    for (int e = 0; e < 4; ++e) {
      const unsigned j = j0 + (unsigned)e;
      const bool wr = j >= 48u;
      const unsigned jj = wr ? j - 48u : j;
      v[e] = (wr ? fn : fa) + lds[(wr ? i1 : i0) * 48u + jj];
    }
    float4 o; o.x = v[0]; o.y = v[1]; o.z = v[2]; o.w = v[3];
    *(float4*)(out + 4u + 4u * (size_t)k) = o;
  }
}

// ---------------- tiny finalize: logZ sum + 4 odd scores elements ----------------
__global__ void crf_finalize_kernel(const float* __restrict__ feat,
                                    const float* __restrict__ trans,
                                    const float* __restrict__ ws,
                                    float* __restrict__ out)
{
  const int t = threadIdx.x;
  float v = (t < 32) ? ws[t] : 0.0f;
#pragma unroll
  for (int off = 32; off; off >>= 1) v += __shfl_xor(v, off, 64);
  if (t == 0) out[0] = v;
  else if (t <= 3) out[t] = feat[0] + trans[t - 1];          // scores_flat[0..2]
  else if (t == 4) out[NSC] = feat[BLT - 1] + trans[2303];   // scores_flat last elem
}

extern "C" void kernel_launch(void* const* d_in, const int* in_sizes, int n_in,
                              void* d_out, int out_size, void* d_ws, size_t ws_size,
                              hipStream_t stream) {
  const float* feat    = (const float*)d_in[0];
  const float* trans   = (const float*)d_in[1];
  const int*   seqLens = (const int*)d_in[2];
  float* out = (float*)d_out;
  float* ws  = (float*)d_ws;

  hipLaunchKernelGGL(crf_fused2_kernel, dim3(2048), dim3(256), 0, stream,
                     feat, trans, seqLens, out, ws);
  hipLaunchKernelGGL(crf_finalize_kernel, dim3(1), dim3(64), 0, stream,
                     feat, trans, ws, out);
}

// Round 3
// 53.786 us; speedup vs baseline: 3.7161x; 1.6544x over previous
//
#include <hip/hip_runtime.h>

#define BB 32
#define LL 512
#define TT 48
#define START_ID 46
#define END_ID 47

constexpr int   BLT  = BB * LL * TT;        // 786432 feature rows-elements
constexpr unsigned NSC = 37748736u;         // B*L*T*T scores elements
constexpr unsigned NGRP = 9437183u;         // float4 groups at scores idx 3+4k

// ---- tree parameters ----
constexpr int SEGS   = 31;                  // segments per batch (16 steps each, t=1..496)
constexpr int SEGLEN = 16;
constexpr int GW     = 1152;                // dwords per 48x48 f16 G matrix
constexpr int NSEG   = BB * SEGS;           // 992
constexpr int SOFF   = NSEG * GW;           // dword offset of Sacc[NSEG]
constexpr int ZOFF   = SOFF + NSEG;         // dword offset of logZ[32]
constexpr size_t WS_NEED = (size_t)(ZOFF + 32) * 4;

typedef __fp16 f16x2 __attribute__((ext_vector_type(2)));
typedef __fp16 f16x8 __attribute__((ext_vector_type(8)));
typedef float  f32x4 __attribute__((ext_vector_type(4)));
typedef unsigned u32x4 __attribute__((ext_vector_type(4)));

__device__ __forceinline__ float fexp2(float x) { return __builtin_amdgcn_exp2f(x); }
__device__ __forceinline__ float flog2(float x) { return __builtin_amdgcn_logf(x); }
__device__ __forceinline__ float rfirst(float x) {
  return __uint_as_float(__builtin_amdgcn_readfirstlane(__float_as_uint(x)));
}
__device__ __forceinline__ float fdot2(f16x2 a, f16x2 b, float c) {
  return __builtin_amdgcn_fdot2(a, b, c, false);
}
__device__ __forceinline__ f16x2 bc(unsigned u) { return __builtin_bit_cast(f16x2, u); }
__device__ __forceinline__ unsigned pk2(float a, float b) {
  return __builtin_bit_cast(unsigned, __builtin_amdgcn_cvt_pkrtz(a, b));
}
__device__ __forceinline__ float dpp_xor1(float x) {
  return __int_as_float(__builtin_amdgcn_update_dpp(
      __float_as_int(x), __float_as_int(x), 0xB1, 0xF, 0xF, true));
}
__device__ __forceinline__ f16x8 b8(unsigned d0, unsigned d1) {
  u32x4 u; u.x = d0; u.y = d1; u.z = 0u; u.w = 0u;
  return __builtin_bit_cast(f16x8, u);
}
__device__ __forceinline__ f32x4 MF(f16x8 a, f16x8 b, f32x4 c) {
  return __builtin_amdgcn_mfma_f32_16x16x32_f16(a, b, c, 0, 0, 0);
}

#define GLD16(gp, lp)                                                        \
  __builtin_amdgcn_global_load_lds(                                          \
      (const __attribute__((address_space(1))) unsigned int*)(gp),           \
      (__attribute__((address_space(3))) unsigned int*)(lp), 16, 0, 0)

// ================= K1: segment-product tree build =================
// wave (b,s): G = A_{16s+16} * ... * A_{16s+1},  A_t = diag(exp f_t) * T
// Fragment placement / zero-pad / C->B repack / rescale-fold verbatim from the
// round-1 correctness-verified MFMA kernel.
__global__ __launch_bounds__(64) void crf_tree_kernel(
    const float* __restrict__ feat, const float* __restrict__ trans,
    unsigned* __restrict__ gws, float* __restrict__ sws)
{
  constexpr float LOG2E = 1.4426950408889634f;
  __shared__ __align__(16) float fls[SEGLEN * 48];     // 3 KiB feat stage
  const int wg = blockIdx.x;
  const int b  = wg / SEGS, s = wg - b * SEGS;
  const int lane = threadIdx.x, col = lane & 15, grp = lane >> 4, rb = grp * 4;

  const char* gbase = (const char*)feat + (size_t)b * 98304 + (size_t)(SEGLEN * s + 1) * 192;
#pragma unroll
  for (int w = 0; w < 3; ++w)
    GLD16(gbase + w * 1024 + lane * 16, (char*)fls + w * 1024);

  // Traw = exp(trans) tiles in f32 (round-1 LDA addressing)
  float4 T_[3][3];
#pragma unroll
  for (int I = 0; I < 3; ++I)
#pragma unroll
    for (int K = 0; K < 3; ++K) {
      const float4 t4 = *(const float4*)(trans + (I * 16 + col) * 48 + K * 16 + rb);
      T_[I][K].x = fexp2(t4.x * LOG2E);
      T_[I][K].y = fexp2(t4.y * LOG2E);
      T_[I][K].z = fexp2(t4.z * LOG2E);
      T_[I][K].w = fexp2(t4.w * LOG2E);
    }

  // B = identity fragments (data dwords only; upper half zero like round-1 mk8)
  unsigned Bd[3][3][2];
#pragma unroll
  for (int K = 0; K < 3; ++K)
#pragma unroll
    for (int J = 0; J < 3; ++J) {
      const float b0 = (K == J && rb + 0 == col) ? 1.f : 0.f;
      const float b1 = (K == J && rb + 1 == col) ? 1.f : 0.f;
      const float b2 = (K == J && rb + 2 == col) ? 1.f : 0.f;
      const float b3 = (K == J && rb + 3 == col) ? 1.f : 0.f;
      Bd[K][J][0] = pk2(b0, b1);
      Bd[K][J][1] = pk2(b2, b3);
    }

  asm volatile("s_waitcnt vmcnt(0)" ::: "memory");
  __builtin_amdgcn_sched_barrier(0);

  float km = 0.f, Sacc = 0.f;
  f32x4 C[3][3];
  const f32x4 zz = {0.f, 0.f, 0.f, 0.f};

  for (int p = 0; p < SEGLEN; ++p) {
    Sacc += km;                                  // km applied to this step's A
    float ef[3];
    ef[0] = fexp2(fmaf(fls[p * 48 +  0 + col], LOG2E, -km));
    ef[1] = fexp2(fmaf(fls[p * 48 + 16 + col], LOG2E, -km));
    ef[2] = fexp2(fmaf(fls[p * 48 + 32 + col], LOG2E, -km));
    f16x8 A_[3][3];
#pragma unroll
    for (int I = 0; I < 3; ++I)
#pragma unroll
      for (int K = 0; K < 3; ++K) {
        u32x4 u;
        u.x = pk2(T_[I][K].x * ef[I], T_[I][K].y * ef[I]);
        u.y = pk2(T_[I][K].z * ef[I], T_[I][K].w * ef[I]);
        u.z = 0u; u.w = 0u;
        A_[I][K] = __builtin_bit_cast(f16x8, u);
      }
#pragma unroll
    for (int I = 0; I < 3; ++I)
#pragma unroll
      for (int J = 0; J < 3; ++J) {
        f32x4 c = MF(A_[I][0], b8(Bd[0][J][0], Bd[0][J][1]), zz);
        c = MF(A_[I][1], b8(Bd[1][J][0], Bd[1][J][1]), c);
        c = MF(A_[I][2], b8(Bd[2][J][0], Bd[2][J][1]), c);
        C[I][J] = c;
      }
    const unsigned u00 = __builtin_amdgcn_readfirstlane(__float_as_uint(C[0][0][0]));
    km = (float)((int)((u00 >> 23) & 255u) - 127);
    // repack C -> B (in-lane, round-1 verified)
#pragma unroll
    for (int K = 0; K < 3; ++K)
#pragma unroll
      for (int J = 0; J < 3; ++J) {
        Bd[K][J][0] = pk2(C[K][J][0], C[K][J][1]);
        Bd[K][J][1] = pk2(C[K][J][2], C[K][J][3]);
      }
  }

  // store G as f16 column-pairs, row-major: dword d of row i = cols (2d, 2d+1)
  const unsigned gb = (unsigned)wg * GW;
#pragma unroll
  for (int I = 0; I < 3; ++I)
#pragma unroll
    for (int J = 0; J < 3; ++J)
#pragma unroll
      for (int r = 0; r < 4; ++r) {
        const float cn = dpp_xor1(C[I][J][r]);           // neighbor col value
        const unsigned pk = pk2(C[I][J][r], cn);
        if (!(col & 1))
          gws[gb + (unsigned)((I * 16 + rb + r) * 24 + ((J * 16 + col) >> 1))] = pk;
      }
  if (lane == 0) sws[SOFF + wg] = Sacc;
}

// ================= K2 phase B: per-batch segment matvecs + tail =================
__device__ __attribute__((noinline)) void crf_phaseB(
    const float* __restrict__ feat, const float* __restrict__ trans,
    const int* __restrict__ seqLens, const unsigned* __restrict__ gws,
    const float* __restrict__ sws, float* __restrict__ zout, int b, int lane)
{
  constexpr float LOG2E = 1.4426950408889634f;
  constexpr float LN2   = 0.6931471805599453f;
  const int ii = lane < 47 ? lane : 47;
  const int Lb = seqLens[b];
  const int steps = Lb - 1;                    // 0..511
  const int nfull = steps >> 4;                // full 16-step segments (<= 31)

  // exp(trans) row ii as f16 pairs (for tail steps) — same as verified kernel
  f16x2 E00,E01,E02,E03,E04,E05,E06,E07,E08,E09,E10,E11,
        E12,E13,E14,E15,E16,E17,E18,E19,E20,E21,E22,E23;
#define LDE(V, J) { const float e0_ = fexp2(trans[ii*48 + 2*(J)]     * LOG2E); \
                    const float e1_ = fexp2(trans[ii*48 + 2*(J) + 1] * LOG2E); \
                    V = __builtin_amdgcn_cvt_pkrtz(e0_, e1_); }
  LDE(E00,0)  LDE(E01,1)  LDE(E02,2)  LDE(E03,3)  LDE(E04,4)  LDE(E05,5)
  LDE(E06,6)  LDE(E07,7)  LDE(E08,8)  LDE(E09,9)  LDE(E10,10) LDE(E11,11)
  LDE(E12,12) LDE(E13,13) LDE(E14,14) LDE(E15,15) LDE(E16,16) LDE(E17,17)
  LDE(E18,18) LDE(E19,19) LDE(E20,20) LDE(E21,21) LDE(E22,22) LDE(E23,23)
#undef LDE
  const float tS = trans[ii * 48 + START_ID];
  const float tE = trans[END_ID * 48 + ii];
  const float* fb = feat + (size_t)b * (LL * TT);

  // init: u0 = exp2(alpha0*LOG2E), normalized by lane-0 anchor
  const float a0 = (tS + fb[ii]) * LOG2E;
  const float anch = rfirst(a0);
  float v = fexp2(a0 - anch);
  float sigma = anch;

#define RL24                                                               \
        unsigned s00,s01,s02,s03,s04,s05,s06,s07,s08,s09,s10,s11,          \
                 s12,s13,s14,s15,s16,s17,s18,s19,s20,s21,s22,s23;          \
        s00=__builtin_amdgcn_readlane(pku,0);  s01=__builtin_amdgcn_readlane(pku,2);  \
        s02=__builtin_amdgcn_readlane(pku,4);  s03=__builtin_amdgcn_readlane(pku,6);  \
        s04=__builtin_amdgcn_readlane(pku,8);  s05=__builtin_amdgcn_readlane(pku,10); \
        s06=__builtin_amdgcn_readlane(pku,12); s07=__builtin_amdgcn_readlane(pku,14); \
        s08=__builtin_amdgcn_readlane(pku,16); s09=__builtin_amdgcn_readlane(pku,18); \
        s10=__builtin_amdgcn_readlane(pku,20); s11=__builtin_amdgcn_readlane(pku,22); \
        s12=__builtin_amdgcn_readlane(pku,24); s13=__builtin_amdgcn_readlane(pku,26); \
        s14=__builtin_amdgcn_readlane(pku,28); s15=__builtin_amdgcn_readlane(pku,30); \
        s16=__builtin_amdgcn_readlane(pku,32); s17=__builtin_amdgcn_readlane(pku,34); \
        s18=__builtin_amdgcn_readlane(pku,36); s19=__builtin_amdgcn_readlane(pku,38); \
        s20=__builtin_amdgcn_readlane(pku,40); s21=__builtin_amdgcn_readlane(pku,42); \
        s22=__builtin_amdgcn_readlane(pku,44); s23=__builtin_amdgcn_readlane(pku,46);

  // ---- segment matvecs: v <- G_s * v ----
  const unsigned* grow = gws + (size_t)(b * SEGS) * GW + ii * 24;
#pragma unroll 2
  for (int s = 0; s < nfull; ++s) {
    const u32x4* gp = (const u32x4*)(grow + (size_t)s * GW);
    const u32x4 g0 = gp[0], g1 = gp[1], g2 = gp[2], g3 = gp[3], g4 = gp[4], g5 = gp[5];
    const float pn = dpp_xor1(v);
    const unsigned pku = pk2(v, pn);
    RL24
    float d0, d1, d2, d3;
    d0 = fdot2(bc(g0.x), bc(s00), 0.0f);
    d1 = fdot2(bc(g0.y), bc(s01), 0.0f);
    d2 = fdot2(bc(g0.z), bc(s02), 0.0f);
    d3 = fdot2(bc(g0.w), bc(s03), 0.0f);
    d0 = fdot2(bc(g1.x), bc(s04), d0);
    d1 = fdot2(bc(g1.y), bc(s05), d1);
    d2 = fdot2(bc(g1.z), bc(s06), d2);
    d3 = fdot2(bc(g1.w), bc(s07), d3);
    d0 = fdot2(bc(g2.x), bc(s08), d0);
    d1 = fdot2(bc(g2.y), bc(s09), d1);
    d2 = fdot2(bc(g2.z), bc(s10), d2);
    d3 = fdot2(bc(g2.w), bc(s11), d3);
    d0 = fdot2(bc(g3.x), bc(s12), d0);
    d1 = fdot2(bc(g3.y), bc(s13), d1);
    d2 = fdot2(bc(g3.z), bc(s14), d2);
    d3 = fdot2(bc(g3.w), bc(s15), d3);
    d0 = fdot2(bc(g4.x), bc(s16), d0);
    d1 = fdot2(bc(g4.y), bc(s17), d1);
    d2 = fdot2(bc(g4.z), bc(s18), d2);
    d3 = fdot2(bc(g4.w), bc(s19), d3);
    d0 = fdot2(bc(g5.x), bc(s20), d0);
    d1 = fdot2(bc(g5.y), bc(s21), d1);
    d2 = fdot2(bc(g5.z), bc(s22), d2);
    d3 = fdot2(bc(g5.w), bc(s23), d3);
    const float dot = (d0 + d1) + (d2 + d3);
    const unsigned ub = __builtin_amdgcn_readfirstlane(__float_as_uint(dot));
    const int e = (int)((ub >> 23) & 255u) - 127;
    v = dot * __uint_as_float((unsigned)(127 - e) << 23);
    sigma += (float)e + sws[SOFF + b * SEGS + s];
  }

  // ---- tail: t = 16*nfull+1 .. steps (<= 15 scalar steps) ----
  int t = nfull * 16 + 1;
  if (t <= steps) {
    float f_cur = fb[(size_t)t * 48 + ii];
    for (; t <= steps; ++t) {
      const int tn = (t + 1 <= steps) ? t + 1 : t;
      const float f_nxt = fb[(size_t)tn * 48 + ii];
      const float pn = dpp_xor1(v);
      const unsigned pku = pk2(v, pn);
      RL24
      float d0, d1, d2, d3;
      d0 = fdot2(E00, bc(s00), 0.0f);
      d1 = fdot2(E01, bc(s01), 0.0f);
      d2 = fdot2(E02, bc(s02), 0.0f);
      d3 = fdot2(E03, bc(s03), 0.0f);
      d0 = fdot2(E04, bc(s04), d0);
      d1 = fdot2(E05, bc(s05), d1);
      d2 = fdot2(E06, bc(s06), d2);
      d3 = fdot2(E07, bc(s07), d3);
      d0 = fdot2(E08, bc(s08), d0);
      d1 = fdot2(E09, bc(s09), d1);
      d2 = fdot2(E10, bc(s10), d2);
      d3 = fdot2(E11, bc(s11), d3);
      d0 = fdot2(E12, bc(s12), d0);
      d1 = fdot2(E13, bc(s13), d1);
      d2 = fdot2(E14, bc(s14), d2);
      d3 = fdot2(E15, bc(s15), d3);
      d0 = fdot2(E16, bc(s16), d0);
      d1 = fdot2(E17, bc(s17), d1);
      d2 = fdot2(E18, bc(s18), d2);
      d3 = fdot2(E19, bc(s19), d3);
      d0 = fdot2(E20, bc(s20), d0);
      d1 = fdot2(E21, bc(s21), d1);
      d2 = fdot2(E22, bc(s22), d2);
      d3 = fdot2(E23, bc(s23), d3);
      const float dot = (d0 + d1) + (d2 + d3);
      const float w = dot * fexp2(f_cur * LOG2E);
      const unsigned ub = __builtin_amdgcn_readfirstlane(__float_as_uint(w));
      const int e = (int)((ub >> 23) & 255u) - 127;
      v = w * __uint_as_float((unsigned)(127 - e) << 23);
      sigma += (float)e;
      f_cur = f_nxt;
    }
  }
#undef RL24

  // capture: logZ_b = (log2(sum_i v_i * 2^(tE*LOG2E)) + sigma) * LN2
  float contrib = (lane < 48) ? v * fexp2(tE * LOG2E) : 0.0f;
#pragma unroll
  for (int off = 32; off; off >>= 1) contrib += __shfl_xor(contrib, off, 64);
  if (lane == 0) zout[b] = (flog2(contrib) + sigma) * LN2;
}

// ================= writer body (shared) =================
__device__ __forceinline__ void scores_writer(
    const float* __restrict__ feat, float* __restrict__ out,
    float* lds, int blk, int nblk)
{
  const unsigned kstride = (unsigned)nblk * 256u;
  unsigned k = (unsigned)blk * 256u + threadIdx.x;
  for (; k < NGRP; k += kstride) {
    const unsigned idx = 3u + 4u * k;
    const unsigned r0 = idx / 48u;
    const unsigned j0 = idx - r0 * 48u;
    const unsigned i0 = r0 % 48u;
    const unsigned rn = (r0 + 1u < (unsigned)BLT) ? r0 + 1u : (unsigned)(BLT - 1);
    const float fa = feat[r0];
    const float fn = feat[rn];
    const unsigned i1 = (i0 + 1u < 48u) ? i0 + 1u : 0u;
    float v[4];
#pragma unroll
    for (int e = 0; e < 4; ++e) {
      const unsigned j = j0 + (unsigned)e;
      const bool wr = j >= 48u;
      const unsigned jj = wr ? j - 48u : j;
      v[e] = (wr ? fn : fa) + lds[(wr ? i1 : i0) * 48u + jj];
    }
    float4 o; o.x = v[0]; o.y = v[1]; o.z = v[2]; o.w = v[3];
    *(float4*)(out + 4u + 4u * (size_t)k) = o;
  }
}

// ================= K2: fused phaseB + writer =================
__global__ __launch_bounds__(256) void crf_fusedB_kernel(
    const float* __restrict__ feat, const float* __restrict__ trans,
    const int* __restrict__ seqLens, float* __restrict__ out,
    const unsigned* __restrict__ gws, float* __restrict__ ws)
{
  __shared__ __align__(16) float lds[2304];
  const int blk = blockIdx.x;
  if (blk < BB) {
    if (threadIdx.x >= 64) return;
    crf_phaseB(feat, trans, seqLens, gws, ws, ws + ZOFF, blk, threadIdx.x);
    return;
  }
  for (int s = threadIdx.x; s < 2304; s += 256) lds[s] = trans[s];
  __syncthreads();
  scores_writer(feat, out, lds, blk - BB, (int)gridDim.x - BB);
}

// ================= finalize (shared by both paths) =================
__global__ void crf_finalize_kernel(const float* __restrict__ feat,
                                    const float* __restrict__ trans,
                                    const float* __restrict__ zws,
                                    float* __restrict__ out)
{
  const int t = threadIdx.x;
  float v = (t < 32) ? zws[t] : 0.0f;
#pragma unroll
  for (int off = 32; off; off >>= 1) v += __shfl_xor(v, off, 64);
  if (t == 0) out[0] = v;
  else if (t <= 3) out[t] = feat[0] + trans[t - 1];
  else if (t == 4) out[NSC] = feat[BLT - 1] + trans[2303];
}

// ================= fallback: verified 88us scalar recursion =================
__device__ __attribute__((noinline)) void crf_recursion_body(
    const float* __restrict__ feat, const float* __restrict__ trans,
    const int* __restrict__ seqLens, float* __restrict__ ws,
    float* lds, int blk, int lane)
{
  constexpr float LOG2E = 1.4426950408889634f;
  const int ii = lane < 47 ? lane : 47;
  const char* gbase = (const char*)(feat + (size_t)blk * (LL * TT));
  const int Lb = seqLens[blk];

#pragma unroll
  for (int w = 0; w < 6; ++w)
    GLD16(gbase + w * 1024 + lane * 16, (char*)&lds[0] + w * 1024);

  f16x2 E00,E01,E02,E03,E04,E05,E06,E07,E08,E09,E10,E11,
        E12,E13,E14,E15,E16,E17,E18,E19,E20,E21,E22,E23;
#define LDE(V, J) { const float e0_ = fexp2(trans[ii*48 + 2*(J)]     * LOG2E); \
                    const float e1_ = fexp2(trans[ii*48 + 2*(J) + 1] * LOG2E); \
                    V = __builtin_amdgcn_cvt_pkrtz(e0_, e1_); }
  LDE(E00,0)  LDE(E01,1)  LDE(E02,2)  LDE(E03,3)  LDE(E04,4)  LDE(E05,5)
  LDE(E06,6)  LDE(E07,7)  LDE(E08,8)  LDE(E09,9)  LDE(E10,10) LDE(E11,11)
  LDE(E12,12) LDE(E13,13) LDE(E14,14) LDE(E15,15) LDE(E16,16) LDE(E17,17)
  LDE(E18,18) LDE(E19,19) LDE(E20,20) LDE(E21,21) LDE(E22,22) LDE(E23,23)
#undef LDE
  const float tS = trans[ii * 48 + START_ID];
  const float tE = trans[END_ID * 48 + ii];

  asm volatile("s_waitcnt vmcnt(0)" ::: "memory");
  __builtin_amdgcn_sched_barrier(0);

  const float f00 = lds[ii];
  float a2 = (tS + f00) * LOG2E;
  float M2 = rfirst(a2) + 5.0f;

  const int nch = (Lb + 31) >> 5;
  for (int c = 0; c < nch; ++c) {
    const bool pre = (c + 1 < nch);
    if (pre) {
      const char* g = gbase + (size_t)(c + 1) * 6144;
      char* l = (char*)&lds[((c + 1) & 1) * 1536];
#pragma unroll
      for (int w = 0; w < 6; ++w) GLD16(g + w * 1024 + lane * 16, l + w * 1024);
    }
    const int tend = ((c + 1) * 32 < Lb) ? (c + 1) * 32 : Lb;
    const int t0 = (c == 0 ? 1 : c * 32);
    const int base = (c & 1) * 1536 + ii;
    if (t0 < tend) {
      float f_cur = lds[base + (t0 - c * 32) * 48];
      for (int t = t0; t < tend; ++t) {
        const int lnxt = ((t + 1 < tend) ? t + 1 : t) - c * 32;
        const float f_nxt = lds[base + lnxt * 48];
        const float p  = fexp2(a2 - M2);
        const float pn = dpp_xor1(p);
        const unsigned pku = pk2(p, pn);
        unsigned s00,s01,s02,s03,s04,s05,s06,s07,s08,s09,s10,s11,
                 s12,s13,s14,s15,s16,s17,s18,s19,s20,s21,s22,s23;
#define RL(K) __builtin_amdgcn_readlane(pku, (K))
        s00=RL(0);  s01=RL(2);  s02=RL(4);  s03=RL(6);
        s04=RL(8);  s05=RL(10); s06=RL(12); s07=RL(14);
        s08=RL(16); s09=RL(18); s10=RL(20); s11=RL(22);
        s12=RL(24); s13=RL(26); s14=RL(28); s15=RL(30);
        s16=RL(32); s17=RL(34); s18=RL(36); s19=RL(38);
        s20=RL(40); s21=RL(42); s22=RL(44); s23=RL(46);
#undef RL
        float d0, d1, d2, d3;
        d0 = fdot2(E00, bc(s00), 0.0f);
        d1 = fdot2(E01, bc(s01), 0.0f);
        d2 = fdot2(E02, bc(s02), 0.0f);
        d3 = fdot2(E03, bc(s03), 0.0f);
        d0 = fdot2(E04, bc(s04), d0);
        d1 = fdot2(E05, bc(s05), d1);
        d2 = fdot2(E06, bc(s06), d2);
        d3 = fdot2(E07, bc(s07), d3);
        d0 = fdot2(E08, bc(s08), d0);
        d1 = fdot2(E09, bc(s09), d1);
        d2 = fdot2(E10, bc(s10), d2);
        d3 = fdot2(E11, bc(s11), d3);
        d0 = fdot2(E12, bc(s12), d0);
        d1 = fdot2(E13, bc(s13), d1);
        d2 = fdot2(E14, bc(s14), d2);
        d3 = fdot2(E15, bc(s15), d3);
        d0 = fdot2(E16, bc(s16), d0);
        d1 = fdot2(E17, bc(s17), d1);
        d2 = fdot2(E18, bc(s18), d2);
        d3 = fdot2(E19, bc(s19), d3);
        d0 = fdot2(E20, bc(s20), d0);
        d1 = fdot2(E21, bc(s21), d1);
        d2 = fdot2(E22, bc(s22), d2);
        d3 = fdot2(E23, bc(s23), d3);
        const float dot = (d0 + d1) + (d2 + d3);
        a2 = fmaf(f_cur, LOG2E, M2 + flog2(dot));
        M2 = rfirst(a2) + 5.0f;
        f_cur = f_nxt;
      }
    }
    asm volatile("s_waitcnt vmcnt(0)" ::: "memory");
    __builtin_amdgcn_sched_barrier(0);
  }

  float last2 = (lane < 48) ? (a2 + tE * LOG2E) : -3.0e38f;
  float m2 = last2;
#pragma unroll
  for (int off = 32; off; off >>= 1) m2 = fmaxf(m2, __shfl_xor(m2, off, 64));
  float e = (lane < 48) ? fexp2(last2 - m2) : 0.0f;
#pragma unroll
  for (int off = 32; off; off >>= 1) e += __shfl_xor(e, off, 64);
  if (lane == 0) ws[blk] = (m2 + flog2(e)) * 0.6931471805599453f;
}

__global__ __launch_bounds__(256) void crf_fused2_kernel(
    const float* __restrict__ feat, const float* __restrict__ trans,
    const int* __restrict__ seqLens, float* __restrict__ out,
    float* __restrict__ ws)
{
  __shared__ __align__(16) float lds[3072];
  const int blk = blockIdx.x;
  if (blk < BB) {
    if (threadIdx.x >= 64) return;
    crf_recursion_body(feat, trans, seqLens, ws, lds, blk, threadIdx.x);
    return;
  }
  for (int s = threadIdx.x; s < 2304; s += 256) lds[s] = trans[s];
  __syncthreads();
  scores_writer(feat, out, lds, blk - BB, (int)gridDim.x - BB);
}

// ================= host =================
extern "C" void kernel_launch(void* const* d_in, const int* in_sizes, int n_in,
                              void* d_out, int out_size, void* d_ws, size_t ws_size,
                              hipStream_t stream) {
  const float* feat    = (const float*)d_in[0];
  const float* trans   = (const float*)d_in[1];
  const int*   seqLens = (const int*)d_in[2];
  float* out = (float*)d_out;
  float* ws  = (float*)d_ws;

  if (ws_size >= WS_NEED) {
    hipLaunchKernelGGL(crf_tree_kernel, dim3(NSEG), dim3(64), 0, stream,
                       feat, trans, (unsigned*)ws, ws);
    hipLaunchKernelGGL(crf_fusedB_kernel, dim3(2048), dim3(256), 0, stream,
                       feat, trans, seqLens, out, (const unsigned*)ws, ws);
    hipLaunchKernelGGL(crf_finalize_kernel, dim3(1), dim3(64), 0, stream,
                       feat, trans, ws + ZOFF, out);
  } else {
    hipLaunchKernelGGL(crf_fused2_kernel, dim3(2048), dim3(256), 0, stream,
                       feat, trans, seqLens, out, ws);
    hipLaunchKernelGGL(crf_finalize_kernel, dim3(1), dim3(64), 0, stream,
                       feat, trans, ws, out);
  }
}